// Round 16
// baseline (91.101 us; speedup 1.0000x reference)
//
#include <hip/hip_runtime.h>
#include <math.h>

typedef _Float16 v8h __attribute__((ext_vector_type(8)));
typedef float v4f __attribute__((ext_vector_type(4)));

constexpr int D      = 256;    // feature dim
constexpr int KS     = 8;      // k-steps of 32 per tile
constexpr int TILE_B = 8192;   // bytes per tile image (16 cand x 256 d x 2B)
constexpr int TPW    = 2;      // tiles per staged window
constexpr int WIN_B  = 16384;  // staged window bytes (2 tiles)
constexpr int NWIN   = 32;     // windows (64 tiles / 2)
#define GUARD 1.0f             // packed-gap bound: >= 1.0 -> true gap >= 0.36 > 0 (pack err <=0.5, f16 dot err <=~0.08)

// ---- pre-pass: codewords -> fp16 image in per-wave-read frag order ----
__global__ void vq_prep(const float* __restrict__ cw, unsigned short* __restrict__ img) {
    int gid = blockIdx.x * 256 + threadIdx.x;   // 0..32767
    int t  = gid >> 9;
    int r  = gid & 511;
    int ks = r >> 6;
    int l  = r & 63;
    int cand = t * 16 + (l & 15);
    int k0   = ks * 32 + (l >> 4) * 8;
    const float* src = cw + (size_t)cand * D + k0;
    float4 t0 = *(const float4*)(src);
    float4 t1 = *(const float4*)(src + 4);
    v8h h;
    h[0] = (_Float16)t0.x; h[1] = (_Float16)t0.y;
    h[2] = (_Float16)t0.z; h[3] = (_Float16)t0.w;
    h[4] = (_Float16)t1.x; h[5] = (_Float16)t1.y;
    h[6] = (_Float16)t1.z; h[7] = (_Float16)t1.w;
    *(v8h*)((char*)img + (size_t)gid * 16) = h;
}

// ---- codeword squared norms (fp32; IDENTICAL to the round-1/5 code that passed) ----
__global__ void vq_csq(const float* __restrict__ cw, float* __restrict__ csq) {
    int k = blockIdx.x * blockDim.x + threadIdx.x;
    const float4* p = reinterpret_cast<const float4*>(cw + (size_t)k * D);
    float s = 0.f;
    #pragma unroll 8
    for (int i = 0; i < D / 4; ++i) {
        float4 v = p[i];
        s += v.x * v.x; s += v.y * v.y; s += v.z * v.z; s += v.w * v.w;
    }
    csq[k] = s;
}

// ---- fused main: 3-buffer LDS pipeline with COUNTED vmcnt (loads stay in
// flight across barriers), setprio around MFMA, then wave-local GUARD epilogue
// (VERBATIM round-7 np-ordered exact rescore for near-tie rows). ----
__launch_bounds__(256, 2)
__global__ void vq_main(const float* __restrict__ inp,
                        const float* __restrict__ cw,
                        const unsigned short* __restrict__ img,
                        const float* __restrict__ csq,
                        float* __restrict__ outq,
                        float* __restrict__ outi,
                        float* __restrict__ bsum) {
    __shared__ __align__(16) char smem[3][WIN_B];   // 48 KB staging
    __shared__ float s_cq[1024];       // csq + 4096 (biased), LDS-resident
    __shared__ int4  s_pack[128];      // per-row packed top-4
    __shared__ float s_xsq[128];       // per-row exact fp32 |x|^2
    __shared__ int   s_win[128];       // per-row winner index
    __shared__ float s_l[4];

    const int tid  = threadIdx.x;
    const int lane = tid & 63;
    const int w    = tid >> 6;              // wave 0..3
    const int lr   = lane & 15;
    const int q    = lane >> 4;             // k-chunk group
    const int base = blockIdx.x * 128 + w * 32;

#define VQ_STAGE(WIN, BUF)                                                           \
    {                                                                                \
        const char* srct = (const char*)img + (size_t)(WIN) * WIN_B;                 \
        _Pragma("unroll")                                                            \
        for (int i = 0; i < 4; ++i) {                                                \
            int off = i * 4096 + w * 1024;                                           \
            __builtin_amdgcn_global_load_lds(                                        \
                (const __attribute__((address_space(1))) unsigned int*)(srct + off + lane * 16), \
                (__attribute__((address_space(3))) unsigned int*)(&smem[BUF][off]),  \
                16, 0, 0);                                                           \
        }                                                                            \
    }

    // stage windows 0 and 1 FIRST so they overlap the A-load/convert
    VQ_STAGE(0, 0)
    VQ_STAGE(1, 1)

    // csq -> LDS (biased by +4096), one float4 per thread
    {
        float4 cv4 = ((const float4*)csq)[tid];
        s_cq[tid * 4 + 0] = cv4.x + 4096.f;
        s_cq[tid * 4 + 1] = cv4.y + 4096.f;
        s_cq[tid * 4 + 2] = cv4.z + 4096.f;
        s_cq[tid * 4 + 3] = cv4.w + 4096.f;
    }

    // load + convert A (pre-scaled by -2, exact); emit exact f32 xsq to LDS
    v8h a2[2][8];
    #pragma unroll
    for (int m = 0; m < 2; ++m) {
        const float* rp = inp + (size_t)(base + m * 16 + lr) * D + q * 8;
        float sq = 0.f;
        #pragma unroll
        for (int ks = 0; ks < KS; ++ks) {
            float4 t0 = *(const float4*)(rp + ks * 32);
            float4 t1 = *(const float4*)(rp + ks * 32 + 4);
            sq = fmaf(t0.x, t0.x, sq); sq = fmaf(t0.y, t0.y, sq);
            sq = fmaf(t0.z, t0.z, sq); sq = fmaf(t0.w, t0.w, sq);
            sq = fmaf(t1.x, t1.x, sq); sq = fmaf(t1.y, t1.y, sq);
            sq = fmaf(t1.z, t1.z, sq); sq = fmaf(t1.w, t1.w, sq);
            v8h h;
            h[0] = (_Float16)(-2.f * t0.x); h[1] = (_Float16)(-2.f * t0.y);
            h[2] = (_Float16)(-2.f * t0.z); h[3] = (_Float16)(-2.f * t0.w);
            h[4] = (_Float16)(-2.f * t1.x); h[5] = (_Float16)(-2.f * t1.y);
            h[6] = (_Float16)(-2.f * t1.z); h[7] = (_Float16)(-2.f * t1.w);
            a2[m][ks] = h;
        }
        sq += __shfl_xor(sq, 16);
        sq += __shfl_xor(sq, 32);
        if (q == 0) s_xsq[w * 32 + m * 16 + lr] = sq;
    }

    const float BIGF = __uint_as_float(0x7F000000u);
    float v1[2][4], v2[2][4];
    #pragma unroll
    for (int m = 0; m < 2; ++m)
        #pragma unroll
        for (int r = 0; r < 4; ++r) { v1[m][r] = BIGF; v2[m][r] = BIGF; }

    // one full drain (vmcnt(0)+lgkmcnt(0)) to publish s_cq/s_xsq; from here on
    // the loop's only vmcnt events are the 4 stage loads per window.
    __syncthreads();

#define VQ_COMPUTE(BUF, WIN)                                                         \
    {                                                                                \
        float cq0 = s_cq[(2 * (WIN)) * 16 + lr];                                     \
        float cq1 = s_cq[(2 * (WIN) + 1) * 16 + lr];                                 \
        v4f a00 = {cq0, cq0, cq0, cq0}; v4f a01 = a00;                               \
        v4f a10 = {cq1, cq1, cq1, cq1}; v4f a11 = a10;                               \
        const char* bb = smem[BUF];                                                  \
        __builtin_amdgcn_s_setprio(1);                                               \
        _Pragma("unroll")                                                            \
        for (int ks = 0; ks < KS; ++ks) {                                            \
            v8h b0 = *(const v8h*)(bb + ks * 1024 + lane * 16);                      \
            v8h b1 = *(const v8h*)(bb + TILE_B + ks * 1024 + lane * 16);             \
            a00 = __builtin_amdgcn_mfma_f32_16x16x32_f16(a2[0][ks], b0, a00, 0, 0, 0); \
            a10 = __builtin_amdgcn_mfma_f32_16x16x32_f16(a2[0][ks], b1, a10, 0, 0, 0); \
            a01 = __builtin_amdgcn_mfma_f32_16x16x32_f16(a2[1][ks], b0, a01, 0, 0, 0); \
            a11 = __builtin_amdgcn_mfma_f32_16x16x32_f16(a2[1][ks], b1, a11, 0, 0, 0); \
        }                                                                            \
        __builtin_amdgcn_s_setprio(0);                                               \
        unsigned idx0 = (unsigned)((2 * (WIN)) * 16) | (unsigned)lr;                 \
        unsigned idx1 = (unsigned)((2 * (WIN) + 1) * 16) | (unsigned)lr;             \
        _Pragma("unroll")                                                            \
        for (int r = 0; r < 4; ++r) {                                                \
            float f;                                                                 \
            f = __uint_as_float(((__float_as_uint(a00[r]) + 0x200u) & 0xFFFFFC00u) | idx0); \
            { float mx = fmaxf(v1[0][r], f); v2[0][r] = fminf(v2[0][r], mx); v1[0][r] = fminf(v1[0][r], f); } \
            f = __uint_as_float(((__float_as_uint(a01[r]) + 0x200u) & 0xFFFFFC00u) | idx0); \
            { float mx = fmaxf(v1[1][r], f); v2[1][r] = fminf(v2[1][r], mx); v1[1][r] = fminf(v1[1][r], f); } \
            f = __uint_as_float(((__float_as_uint(a10[r]) + 0x200u) & 0xFFFFFC00u) | idx1); \
            { float mx = fmaxf(v1[0][r], f); v2[0][r] = fminf(v2[0][r], mx); v1[0][r] = fminf(v1[0][r], f); } \
            f = __uint_as_float(((__float_as_uint(a11[r]) + 0x200u) & 0xFFFFFC00u) | idx1); \
            { float mx = fmaxf(v1[1][r], f); v2[1][r] = fminf(v2[1][r], mx); v1[1][r] = fminf(v1[1][r], f); } \
        }                                                                            \
    }

    // main loop: counted vmcnt(4) keeps the younger window's loads in flight
    // across the barrier; 3-buffer rotation makes one barrier/window safe.
    int cm = 0;            // compute buffer index (win % 3)
    int st = 2;            // stage buffer index ((win+2) % 3)
    for (int win = 0; win < NWIN - 1; ++win) {
        asm volatile("s_waitcnt vmcnt(4)" ::: "memory");
        __builtin_amdgcn_s_barrier();
        __builtin_amdgcn_sched_barrier(0);
        if (win + 2 < NWIN) VQ_STAGE(win + 2, st)
        __builtin_amdgcn_sched_barrier(0);
        VQ_COMPUTE(cm, win)
        cm = (cm == 2) ? 0 : cm + 1;
        st = (st == 2) ? 0 : st + 1;
    }
    asm volatile("s_waitcnt vmcnt(0)" ::: "memory");
    __builtin_amdgcn_s_barrier();
    __builtin_amdgcn_sched_barrier(0);
    VQ_COMPUTE(cm, NWIN - 1)
#undef VQ_COMPUTE
#undef VQ_STAGE

    // bitonic merge of packed sorted-2 (padded to 4) across the 16 lanes per row
    #pragma unroll
    for (int m = 0; m < 2; ++m)
        #pragma unroll
        for (int r = 0; r < 4; ++r) {
            float L0 = v1[m][r], L1 = v2[m][r], L2 = BIGF, L3 = BIGF;
            #pragma unroll
            for (int off = 8; off; off >>= 1) {
                float P0 = __shfl_xor(L0, off, 16);
                float P1 = __shfl_xor(L1, off, 16);
                float P2 = __shfl_xor(L2, off, 16);
                float P3 = __shfl_xor(L3, off, 16);
                float M0 = fminf(L0, P3), M1 = fminf(L1, P2);
                float M2 = fminf(L2, P1), M3 = fminf(L3, P0);
                float a0 = fminf(M0, M2), c0 = fmaxf(M0, M2);
                float b0 = fminf(M1, M3), d0 = fmaxf(M1, M3);
                L0 = fminf(a0, b0); L1 = fmaxf(a0, b0);
                L2 = fminf(c0, d0); L3 = fmaxf(c0, d0);
            }
            if (lr == 0) {
                int rloc = m * 16 + q * 4 + r;         // 0..31 within wave
                s_pack[w * 32 + rloc] = make_int4(
                    (int)__float_as_uint(L0), (int)__float_as_uint(L1),
                    (int)__float_as_uint(L2), (int)__float_as_uint(L3));
            }
        }
    // wave-local LDS round-trip (writer == reader wave); compiler inserts lgkmcnt

    // ---- fused epilogue: 4 lanes per row over the wave's 32 rows ----
    const int c = lane & 3;
    float lacc = 0.f;
    #pragma unroll
    for (int h = 0; h < 2; ++h) {
        int rloc = h * 16 + (lane >> 2);               // 0..31 within wave
        int grow = base + rloc;
        int4 pk = s_pack[w * 32 + rloc];
        float L0 = __uint_as_float((unsigned)pk.x);
        float L1 = __uint_as_float((unsigned)pk.y);
        float L2 = __uint_as_float((unsigned)pk.z);
        float L3 = __uint_as_float((unsigned)pk.w);
        float xq = s_xsq[w * 32 + rloc];

        int   bi;
        float bd;
        bool rescue = (L1 - L0) < GUARD;               // uniform across the 4-lane group
        if (rescue) {
            float Lc = (c == 0) ? L0 : (c == 1) ? L1 : (c == 2) ? L2 : L3;
            int cd = (int)(__float_as_uint(Lc) & 1023u);
            const float4* xp = (const float4*)(inp + (size_t)grow * D);
            const float4* cp = (const float4*)(cw + (size_t)cd * D);
            float dot = 0.f, xsq = 0.f;
            #pragma unroll 8
            for (int i = 0; i < D / 4; ++i) {
                float4 xv = xp[i];
                float4 cv = cp[i];
                xsq = fmaf(xv.x, xv.x, xsq);
                xsq = fmaf(xv.y, xv.y, xsq);
                xsq = fmaf(xv.z, xv.z, xsq);
                xsq = fmaf(xv.w, xv.w, xsq);
                dot = fmaf(xv.x, cv.x, dot);
                dot = fmaf(xv.y, cv.y, dot);
                dot = fmaf(xv.z, cv.z, dot);
                dot = fmaf(xv.w, cv.w, dot);
            }
            float m2 = dot + dot;
            float t  = xsq - m2;
            float e  = t + csq[cd];
            bd = e; bi = cd;
            #pragma unroll
            for (int off = 1; off <= 2; off <<= 1) {
                float ev = __shfl_xor(bd, off, 4);
                int   iv = __shfl_xor(bi, off, 4);
                bool  tk = (ev < bd) || (ev == bd && iv < bi);
                bd = tk ? ev : bd;
                bi = tk ? iv : bi;
            }
        } else {
            bi = (int)(__float_as_uint(L0) & 1023u);
            bd = (L0 - 4096.f) + xq;                   // approx dist (loss only)
        }

        if (c == 0) { s_win[w * 32 + rloc] = bi; lacc += bd; }
    }

    // gather winning codewords (L2-resident) -> coalesced outq write
    #pragma unroll 4
    for (int rr = 0; rr < 32; ++rr) {
        int bw = s_win[w * 32 + rr];                   // wave-uniform broadcast
        float4 cv = *(const float4*)(cw + (size_t)bw * D + lane * 4);
        *(float4*)(outq + (size_t)(base + rr) * D + lane * 4) = cv;
        if (lane == 0) outi[base + rr] = (float)bw;
    }

    // block loss partial (deterministic)
    #pragma unroll
    for (int off = 32; off; off >>= 1) lacc += __shfl_xor(lacc, off);
    if (lane == 0) s_l[w] = lacc;
    __syncthreads();
    if (tid == 0) bsum[blockIdx.x] = s_l[0] + s_l[1] + s_l[2] + s_l[3];
}

// ---- deterministic loss reduction ----
__global__ void vq_finalize(const float* __restrict__ bsum, float* __restrict__ out_loss,
                            int nb, float scale) {
    __shared__ float s[4];
    int tid = threadIdx.x;
    float v = 0.f;
    for (int i = tid; i < nb; i += 256) v += bsum[i];
    #pragma unroll
    for (int off = 32; off; off >>= 1) v += __shfl_down(v, off, 64);
    if ((tid & 63) == 0) s[tid >> 6] = v;
    __syncthreads();
    if (tid == 0) out_loss[0] = (s[0] + s[1] + s[2] + s[3]) * scale;
}

extern "C" void kernel_launch(void* const* d_in, const int* in_sizes, int n_in,
                              void* d_out, int out_size, void* d_ws, size_t ws_size,
                              hipStream_t stream) {
    const float* inp = (const float*)d_in[0];
    const float* cw  = (const float*)d_in[1];
    float* out = (float*)d_out;
    const int N = in_sizes[0] / D;   // 65536
    const int K = in_sizes[1] / D;   // 1024

    char* ws = (char*)d_ws;
    unsigned short* img = (unsigned short*)ws;            // 512 KB fp16 image
    float* csq  = (float*)(ws + (size_t)K * D * 2);       // 4 KB
    float* bsum = csq + K;                                // 2 KB (512 partials)

    float* outq = out;
    float* outi = out + (size_t)N * D;
    float* outl = outi + N;

    vq_prep<<<dim3((K * 32) / 256), dim3(256), 0, stream>>>(cw, img);
    vq_csq<<<dim3(K / 256), dim3(256), 0, stream>>>(cw, csq);

    // 32 rows/wave, 128 rows/block -> 512 blocks (2/CU), fused epilogue
    vq_main<<<dim3(N / 128), dim3(256), 0, stream>>>(inp, cw, img, csq,
                                                     outq, outi, bsum);
    vq_finalize<<<dim3(1), dim3(256), 0, stream>>>(bsum, outl, N / 128,
                                                   1.25f / ((float)N * (float)D));
}